// Round 14
// baseline (273.649 us; speedup 1.0000x reference)
//
#include <hip/hip_runtime.h>
#include <stdint.h>

typedef __attribute__((ext_vector_type(8))) short short8;
typedef __attribute__((ext_vector_type(4))) short short4v;
typedef __attribute__((ext_vector_type(4))) float floatx4;

#define QSCALE 0.1803368801111f /* 0.125 * log2(e): S in log2 units */

__device__ __forceinline__ unsigned short f2bf(float f) {
  unsigned int u = __float_as_uint(f);
  unsigned int r = (u + 0x7FFFu + ((u >> 16) & 1u)) >> 16;  // RNE
  return (unsigned short)r;
}

__device__ __forceinline__ unsigned int cvt_pk_bf16(float lo, float hi) {
  unsigned int r;
  asm("v_cvt_pk_bf16_f32 %0, %1, %2" : "=v"(r) : "v"(lo), "v"(hi));
  return r;
}

__device__ __forceinline__ float max3f(float a, float b, float c) {
  float r;
  asm("v_max3_f32 %0, %1, %2, %3" : "=v"(r) : "v"(a), "v"(b), "v"(c));
  return r;
}

__device__ __forceinline__ float max16(const floatx4& a, const floatx4& b,
                                       const floatx4& c, const floatx4& d) {
  float m1 = max3f(a[0], a[1], a[2]);
  float m2 = max3f(a[3], b[0], b[1]);
  float m3 = max3f(b[2], b[3], c[0]);
  float m4 = max3f(c[1], c[2], c[3]);
  float m5 = max3f(d[0], d[1], d[2]);
  float r1 = max3f(m1, m2, m3);
  float r2 = max3f(m4, m5, d[3]);
  return fmaxf(r1, r2);
}

__device__ __forceinline__ void async_copy16(void* lds, const void* g) {
  __builtin_amdgcn_global_load_lds(
      (const __attribute__((address_space(1))) unsigned int*)g,
      (__attribute__((address_space(3))) unsigned int*)lds, 16, 0, 0);
}

// ---------------------------------------------------------------------------
// ALL fp32 -> bf16 conversions in one launch.
// ---------------------------------------------------------------------------
__global__ __launch_bounds__(256) void f2ball_kernel(
    const float* __restrict__ x, unsigned short* __restrict__ xb,
    const float* __restrict__ w0, const float* __restrict__ w1,
    const float* __restrict__ w2, const float* __restrict__ w3,
    unsigned short* __restrict__ o0, unsigned short* __restrict__ o1,
    unsigned short* __restrict__ o2, unsigned short* __restrict__ o3) {
  const float* in;
  unsigned short* out;
  long i;
  if (blockIdx.x < 8192) {
    in = x;
    out = xb;
    i = (long)blockIdx.x * 256 + threadIdx.x;
  } else {
    int wb = blockIdx.x - 8192;
    int which = wb >> 10;
    in = (which == 0) ? w0 : (which == 1) ? w1 : (which == 2) ? w2 : w3;
    out = (which == 0) ? o0 : (which == 1) ? o1 : (which == 2) ? o2 : o3;
    i = (long)(wb & 1023) * 256 + threadIdx.x;
  }
  float4 v = ((const float4*)in)[i];
  short4v o;
  o[0] = (short)f2bf(v.x);
  o[1] = (short)f2bf(v.y);
  o[2] = (short)f2bf(v.z);
  o[3] = (short)f2bf(v.w);
  *(short4v*)(out + i * 4) = o;
}

// ---------------------------------------------------------------------------
// Double-buffered 2-phase GEMM mainloop (1 barrier per K-step).
// ---------------------------------------------------------------------------
__device__ __forceinline__ void gemm128_mainloop_db(
    const unsigned short* __restrict__ A, const unsigned short* __restrict__ Bt,
    int K, long brow, long bcol, unsigned short* As, unsigned short* Bs,
    floatx4 acc[4][4]) {
  const int tid = threadIdx.x;
  const int wave = tid >> 6;
  const int lane = tid & 63;
  const int wr = wave >> 1, wc = wave & 1;
  const int lr = lane & 15, lg = lane >> 4;

  const unsigned short* ga = A + (brow + (tid >> 2)) * (long)K + (tid & 3) * 8;
  const unsigned short* gb = Bt + (bcol + (tid >> 2)) * (long)K + (tid & 3) * 8;
  const int woff = wave * 512;
  const int a_off = (wr * 64 + lr) * 32 + lg * 8;
  const int b_off = (wc * 64 + lr) * 32 + lg * 8;

  async_copy16(As + woff, ga);
  async_copy16(As + woff + 2048, ga + (long)64 * K);
  async_copy16(Bs + woff, gb);
  async_copy16(Bs + woff + 2048, gb + (long)64 * K);
  ga += 32;
  gb += 32;
  __syncthreads();

  int buf = 0;
  for (int kt = 0; kt < K; kt += 32) {
    if (kt + 32 < K) {
      unsigned short* lA = As + (buf ^ 1) * 4096 + woff;
      unsigned short* lB = Bs + (buf ^ 1) * 4096 + woff;
      async_copy16(lA, ga);
      async_copy16(lA + 2048, ga + (long)64 * K);
      async_copy16(lB, gb);
      async_copy16(lB + 2048, gb + (long)64 * K);
      ga += 32;
      gb += 32;
    }
    const unsigned short* Ab = As + buf * 4096;
    const unsigned short* Bb = Bs + buf * 4096;
    short8 af[4], bf[4];
#pragma unroll
    for (int i = 0; i < 4; ++i) {
      af[i] = *(const short8*)(Ab + a_off + i * 512);
      bf[i] = *(const short8*)(Bb + b_off + i * 512);
    }
#pragma unroll
    for (int i = 0; i < 4; ++i)
#pragma unroll
      for (int j = 0; j < 4; ++j)
        acc[i][j] = __builtin_amdgcn_mfma_f32_16x16x32_bf16(af[i], bf[j], acc[i][j], 0, 0, 0);
    __syncthreads();
    buf ^= 1;
  }
}

// ---------------------------------------------------------------------------
// QKV projection. Q pre-scaled to log2 units. V-epilogue transposes the
// 128x128 tile through LDS so vt stores are 16B-contiguous in t.
// ---------------------------------------------------------------------------
__global__ __launch_bounds__(256, 4) void qkv_gemm(
    const unsigned short* __restrict__ xb, const unsigned short* __restrict__ wqkv,
    const float* __restrict__ bq, const float* __restrict__ bk,
    const float* __restrict__ bv, unsigned short* __restrict__ q_out,
    unsigned short* __restrict__ k_out, unsigned short* __restrict__ vt_out) {
  __shared__ __align__(16) unsigned short Sh[128 * 136];  // 34 KB
  unsigned short* As = Sh;
  unsigned short* Bs = Sh + 8192;
  floatx4 zero = {0.f, 0.f, 0.f, 0.f};
  floatx4 acc[4][4];
#pragma unroll
  for (int i = 0; i < 4; ++i)
#pragma unroll
    for (int j = 0; j < 4; ++j) acc[i][j] = zero;

  long brow = (long)blockIdx.x * 128;
  long bcol = (long)blockIdx.y * 128;
  gemm128_mainloop_db(xb, wqkv, 1024, brow, bcol, As, Bs, acc);

  const int wave = threadIdx.x >> 6, lane = threadIdx.x & 63;
  const int wr = wave >> 1, wc = wave & 1, lr = lane & 15, lg = lane >> 4;
  const int kind = (int)(bcol >> 10);
  const float* bias = (kind == 0) ? bq : (kind == 1 ? bk : bv);

  if (kind == 2) {
#pragma unroll
    for (int i = 0; i < 4; ++i)
#pragma unroll
      for (int j = 0; j < 4; ++j) {
        int n_local = wc * 64 + j * 16 + lr;
        int m_base = wr * 64 + i * 16 + lg * 4;
        float bsc = bias[(int)((bcol + n_local) & 1023)];
        short4v pk;
#pragma unroll
        for (int r = 0; r < 4; ++r) pk[r] = (short)f2bf(acc[i][j][r] + bsc);
        *(short4v*)(Sh + n_local * 136 + m_base) = pk;
      }
    __syncthreads();
    const int b = (int)(brow >> 11);
    const int t0 = (int)(brow & 2047);
    const int f0 = (int)(bcol - 2048);
#pragma unroll
    for (int p = 0; p < 8; ++p) {
      int c = p * 256 + threadIdx.x;
      int d_loc = c >> 4, tc = c & 15;
      short8 v = *(const short8*)(Sh + d_loc * 136 + tc * 8);
      int h = (f0 >> 6) + (d_loc >> 6);
      int d = d_loc & 63;
      *(short8*)(vt_out + ((long)((b * 16 + h) * 64 + d)) * 2048 + t0 + tc * 8) = v;
    }
  } else {
#pragma unroll
    for (int i = 0; i < 4; ++i)
#pragma unroll
      for (int j = 0; j < 4; ++j)
#pragma unroll
        for (int r = 0; r < 4; ++r) {
          int m = (int)brow + wr * 64 + i * 16 + lg * 4 + r;
          int n = (int)bcol + wc * 64 + j * 16 + lr;
          int f = n & 1023;
          float v = acc[i][j][r] + bias[f];
          if (kind == 0) v *= QSCALE;
          unsigned short o = f2bf(v);
          int h = f >> 6, d = f & 63;
          int bb = m >> 11, t = m & 2047;
          long bh = (long)(bb * 16 + h);
          if (kind == 0)
            q_out[(bh * 2048 + t) * 64 + d] = o;
          else
            k_out[(bh * 2048 + t) * 64 + d] = o;
        }
  }
}

// ---------------------------------------------------------------------------
// Flash attention helpers (v10 structure)
// ---------------------------------------------------------------------------
__device__ __forceinline__ void stage_kv(char* __restrict__ Kb, char* __restrict__ Vb,
                                         const char* __restrict__ Kp,
                                         const char* __restrict__ Vt, int kv0,
                                         int tid) {
  const int wave = tid >> 6;
#pragma unroll
  for (int j = 0; j < 2; ++j) {
    int d = j * 256 + tid;  // chunk id 0..511
    int row = d >> 3, cc = d & 7;
    int gc = cc ^ (row & 7);
    const char* gk = Kp + (size_t)kv0 * 128 + row * 128 + gc * 16;
    async_copy16(Kb + (j * 256 + wave * 64) * 16, gk);
    const char* gv = Vt + (size_t)row * 4096 + (size_t)kv0 * 2 + gc * 16;
    async_copy16(Vb + (j * 256 + wave * 64) * 16, gv);
  }
}

__device__ __forceinline__ void attn_step(
    const char* __restrict__ Kb, const char* __restrict__ Vb,
    char* __restrict__ PTw, const short8 (&qf)[2][2],
    int kv0, int q0, int lr, int lg, bool diag,
    float (&m_i)[2], floatx4 (&accL)[2], floatx4 (&accO)[2][4]) {
  floatx4 zero = {0.f, 0.f, 0.f, 0.f};
  const int x7 = lr & 7;
  floatx4 s[2][4];
  __builtin_amdgcn_s_setprio(1);
#pragma unroll
  for (int nt = 0; nt < 4; ++nt) {
    const char* kr = Kb + (nt * 16 + lr) * 128;
    short8 kf0 = *(const short8*)(kr + ((lg ^ x7) * 16));
    short8 kf1 = *(const short8*)(kr + (((4 + lg) ^ x7) * 16));
#pragma unroll
    for (int qa = 0; qa < 2; ++qa) {
      floatx4 a = zero;
      a = __builtin_amdgcn_mfma_f32_16x16x32_bf16(kf0, qf[qa][0], a, 0, 0, 0);
      a = __builtin_amdgcn_mfma_f32_16x16x32_bf16(kf1, qf[qa][1], a, 0, 0, 0);
      s[qa][nt] = a;
    }
  }
  __builtin_amdgcn_s_setprio(0);

  if (diag) {
#pragma unroll
    for (int qa = 0; qa < 2; ++qa) {
      const int q = q0 + qa * 16 + lr;
#pragma unroll
      for (int nt = 0; nt < 4; ++nt)
#pragma unroll
        for (int r = 0; r < 4; ++r) {
          int kvi = kv0 + nt * 16 + lg * 4 + r;
          if (kvi > q) s[qa][nt][r] = -1e30f;
        }
    }
  }

  float pmax[2];
#pragma unroll
  for (int qa = 0; qa < 2; ++qa)
    pmax[qa] = max16(s[qa][0], s[qa][1], s[qa][2], s[qa][3]);

  float g = fmaxf(pmax[0] - m_i[0], pmax[1] - m_i[1]);
  if (__any(g > 11.5f)) {
#pragma unroll
    for (int qa = 0; qa < 2; ++qa) {
      float mx = fmaxf(pmax[qa], __shfl_xor(pmax[qa], 16));
      mx = fmaxf(mx, __shfl_xor(mx, 32));
      float mnew = fmaxf(m_i[qa], mx);
      float scl = exp2f(m_i[qa] - mnew);
      m_i[qa] = mnew;
#pragma unroll
      for (int r = 0; r < 4; ++r) {
        float so = __shfl(scl, lg * 4 + r);
        accL[qa][r] *= so;
#pragma unroll
        for (int dt = 0; dt < 4; ++dt) accO[qa][dt][r] *= so;
      }
    }
  }

#pragma unroll
  for (int qa = 0; qa < 2; ++qa) {
    char* prow = PTw + (qa * 16 + lr) * 128;
#pragma unroll
    for (int nt = 0; nt < 4; ++nt) {
      float p0 = exp2f(s[qa][nt][0] - m_i[qa]);
      float p1 = exp2f(s[qa][nt][1] - m_i[qa]);
      float p2 = exp2f(s[qa][nt][2] - m_i[qa]);
      float p3 = exp2f(s[qa][nt][3] - m_i[qa]);
      uint2 wv;
      wv.x = cvt_pk_bf16(p0, p1);
      wv.y = cvt_pk_bf16(p2, p3);
      *(uint2*)(prow + (((2 * nt + (lg >> 1)) ^ x7) * 16) + ((2 * lg) & 3) * 4) = wv;
    }
  }

  short8 ones;
#pragma unroll
  for (int j = 0; j < 8; ++j) ones[j] = (short)0x3F80;

  __builtin_amdgcn_s_setprio(1);
#pragma unroll
  for (int kk = 0; kk < 2; ++kk) {
    short8 pf0 = *(const short8*)(PTw + lr * 128 + (((4 * kk + lg) ^ x7) * 16));
    short8 pf1 = *(const short8*)(PTw + (16 + lr) * 128 + (((4 * kk + lg) ^ x7) * 16));
#pragma unroll
    for (int dt = 0; dt < 4; ++dt) {
      short8 vf = *(const short8*)(Vb + (dt * 16 + lr) * 128 + (((4 * kk + lg) ^ x7) * 16));
      accO[0][dt] = __builtin_amdgcn_mfma_f32_16x16x32_bf16(pf0, vf, accO[0][dt], 0, 0, 0);
      accO[1][dt] = __builtin_amdgcn_mfma_f32_16x16x32_bf16(pf1, vf, accO[1][dt], 0, 0, 0);
    }
    accL[0] = __builtin_amdgcn_mfma_f32_16x16x32_bf16(pf0, ones, accL[0], 0, 0, 0);
    accL[1] = __builtin_amdgcn_mfma_f32_16x16x32_bf16(pf1, ones, accL[1], 0, 0, 0);
  }
  __builtin_amdgcn_s_setprio(0);
}

// ---------------------------------------------------------------------------
// Fused attn + output-projection kernel (1536 blocks):
//   blocks [0,1024)   : flash attention v10 (LPT: qt = 15 - id/64, bh = id%64)
//   blocks [1024,1536): out = O @ Wo^T + bo, 128x128 tiles; each block
//                       spin-waits on cnt[b*16+qt] == 16 (its 16 attn
//                       head-blocks) before reading ob.
// attn never waits -> deadlock-free for any dispatch/placement. cnt is
// zeroed via hipMemsetAsync before launch (xb region, dead after qkv).
// ---------------------------------------------------------------------------
__global__ __launch_bounds__(256, 3) void attn_out_fused(
    const unsigned short* __restrict__ qb, const unsigned short* __restrict__ kb,
    const unsigned short* __restrict__ vtb, unsigned short* __restrict__ ob,
    const unsigned short* __restrict__ wo, const float* __restrict__ bo,
    float* __restrict__ out, unsigned int* __restrict__ cnt) {
  __shared__ __align__(16) char Lds[49152];
  const int tid = threadIdx.x;
  floatx4 zero = {0.f, 0.f, 0.f, 0.f};

  if (blockIdx.x < 1024) {
    // ======================= attention =======================
    char* Kbuf = Lds;           // [2][8192]
    char* Vbuf = Lds + 16384;   // [2][8192]
    char* PTb = Lds + 32768;    // [4][4096]

    const int id = blockIdx.x;
    const int qt = 15 - (id >> 6);
    const int bh = id & 63;

    const int wave = tid >> 6, lane = tid & 63;
    const int lr = lane & 15, lg = lane >> 4;
    const unsigned short* Q = qb + (long)bh * 2048 * 64;
    const char* Kp = (const char*)(kb + (long)bh * 2048 * 64);
    const char* Vt = (const char*)(vtb + (long)bh * 64 * 2048);
    const int b = bh >> 4, h = bh & 15;
    char* PTw = PTb + wave * 4096;

    const int q0 = qt * 128 + wave * 32;
    const int nkv = 2 * qt + 2;

    short8 qf[2][2];
#pragma unroll
    for (int qa = 0; qa < 2; ++qa)
#pragma unroll
      for (int kk = 0; kk < 2; ++kk)
        qf[qa][kk] = *(const short8*)(Q + (q0 + qa * 16 + lr) * 64 + kk * 32 + lg * 8);

    floatx4 accO[2][4];
    floatx4 accL[2];
#pragma unroll
    for (int qa = 0; qa < 2; ++qa) {
      accL[qa] = zero;
#pragma unroll
      for (int dt = 0; dt < 4; ++dt) accO[qa][dt] = zero;
    }
    float m_i[2] = {-1e30f, -1e30f};

    stage_kv(Kbuf, Vbuf, Kp, Vt, 0, tid);
    __syncthreads();
#pragma unroll 1
    for (int kv = 0; kv < nkv; ++kv) {
      if (kv + 1 < nkv)
        stage_kv(Kbuf + ((kv + 1) & 1) * 8192, Vbuf + ((kv + 1) & 1) * 8192, Kp, Vt,
                 (kv + 1) * 64, tid);
      const int kv0 = kv * 64;
      if (kv0 < q0 + 32)
        attn_step(Kbuf + (kv & 1) * 8192, Vbuf + (kv & 1) * 8192, PTw, qf, kv0, q0,
                  lr, lg, kv0 + 64 > q0, m_i, accL, accO);
      __syncthreads();
    }

#pragma unroll
    for (int qa = 0; qa < 2; ++qa) {
#pragma unroll
      for (int r = 0; r < 4; ++r) {
        float io = 1.f / accL[qa][r];
        int tq = q0 + qa * 16 + 4 * lg + r;
#pragma unroll
        for (int dt = 0; dt < 4; ++dt)
          ob[((long)b * 2048 + tq) * 1024 + h * 64 + dt * 16 + lr] =
              f2bf(accO[qa][dt][r] * io);
      }
    }
    // signal completion of this (b, qt) head-slice
    __syncthreads();
    if (tid == 0) {
      __threadfence();
      atomicAdd(&cnt[b * 16 + qt], 1u);
    }
  } else {
    // ==================== output projection ====================
    const int oid = blockIdx.x - 1024;
    long brow = (long)(oid >> 3) * 128;
    long bcol = (long)(oid & 7) * 128;

    // wait until all 16 attn head-blocks for this row-group are done
    if (tid == 0) {
      while (atomicAdd(&cnt[(int)(brow >> 7)], 0u) < 16u)
        __builtin_amdgcn_s_sleep(8);
    }
    __syncthreads();
    __threadfence();

    unsigned short* As = (unsigned short*)Lds;
    unsigned short* Bs = (unsigned short*)(Lds + 16384);
    floatx4 acc[4][4];
#pragma unroll
    for (int i = 0; i < 4; ++i)
#pragma unroll
      for (int j = 0; j < 4; ++j) acc[i][j] = zero;

    gemm128_mainloop_db(ob, wo, 1024, brow, bcol, As, Bs, acc);

    const int wave = tid >> 6, lane = tid & 63;
    const int wr = wave >> 1, wc = wave & 1, lr = lane & 15, lg = lane >> 4;
#pragma unroll
    for (int i = 0; i < 4; ++i)
#pragma unroll
      for (int j = 0; j < 4; ++j)
#pragma unroll
        for (int r = 0; r < 4; ++r) {
          int m = (int)brow + wr * 64 + i * 16 + lg * 4 + r;
          int n = (int)bcol + wc * 64 + j * 16 + lr;
          out[(long)m * 1024 + n] = acc[i][j][r] + bo[n];
        }
  }
}

// ---------------------------------------------------------------------------
extern "C" void kernel_launch(void* const* d_in, const int* in_sizes, int n_in,
                              void* d_out, int out_size, void* d_ws, size_t ws_size,
                              hipStream_t stream) {
  const float* x = (const float*)d_in[0];
  const float* bq = (const float*)d_in[2];
  const float* bk = (const float*)d_in[4];
  const float* bv = (const float*)d_in[6];
  const float* bo = (const float*)d_in[8];
  float* out = (float*)d_out;

  char* ws = (char*)d_ws;
  unsigned short* xb = (unsigned short*)(ws);                  // 16 MB  [8192][1024]
  unsigned short* wqkv = (unsigned short*)(ws + (16l << 20));  // 6 MB   [3072][1024]
  unsigned short* wob = (unsigned short*)(ws + (22l << 20));   // 2 MB   [1024][1024]
  unsigned short* qb = (unsigned short*)(ws + (24l << 20));    // 16 MB  [64][2048][64]
  unsigned short* kb = (unsigned short*)(ws + (40l << 20));    // 16 MB  [64][2048][64]
  unsigned short* vtb = (unsigned short*)(ws + (56l << 20));   // 16 MB  [64][64][2048]
  unsigned short* ob = (unsigned short*)(ws + (72l << 20));    // 16 MB  [8192][1024]
  unsigned int* cnt = (unsigned int*)ws;  // reuses xb region (dead after qkv)

  f2ball_kernel<<<12288, 256, 0, stream>>>(
      x, xb, (const float*)d_in[1], (const float*)d_in[3], (const float*)d_in[5],
      (const float*)d_in[7], wqkv, wqkv + (1l << 20), wqkv + (2l << 20), wob);

  qkv_gemm<<<dim3(64, 24), 256, 0, stream>>>(xb, wqkv, bq, bk, bv, qb, kb, vtb);

  // zero the 64 dependency counters (stream-ordered after qkv's last xb read)
  hipMemsetAsync(cnt, 0, 64 * sizeof(unsigned int), stream);

  attn_out_fused<<<1536, 256, 0, stream>>>(qb, kb, vtb, ob, wob, bo, out, cnt);
}

// Round 15
// 164.363 us; speedup vs baseline: 1.6649x; 1.6649x over previous
//
#include <hip/hip_runtime.h>
#include <stdint.h>

typedef __attribute__((ext_vector_type(8))) short short8;
typedef __attribute__((ext_vector_type(4))) short short4v;
typedef __attribute__((ext_vector_type(4))) float floatx4;

#define QSCALE 0.1803368801111f /* 0.125 * log2(e): S in log2 units */

__device__ __forceinline__ unsigned short f2bf(float f) {
  unsigned int u = __float_as_uint(f);
  unsigned int r = (u + 0x7FFFu + ((u >> 16) & 1u)) >> 16;  // RNE
  return (unsigned short)r;
}

__device__ __forceinline__ unsigned int cvt_pk_bf16(float lo, float hi) {
  unsigned int r;
  asm("v_cvt_pk_bf16_f32 %0, %1, %2" : "=v"(r) : "v"(lo), "v"(hi));
  return r;
}

__device__ __forceinline__ float max3f(float a, float b, float c) {
  float r;
  asm("v_max3_f32 %0, %1, %2, %3" : "=v"(r) : "v"(a), "v"(b), "v"(c));
  return r;
}

__device__ __forceinline__ float max16(const floatx4& a, const floatx4& b,
                                       const floatx4& c, const floatx4& d) {
  float m1 = max3f(a[0], a[1], a[2]);
  float m2 = max3f(a[3], b[0], b[1]);
  float m3 = max3f(b[2], b[3], c[0]);
  float m4 = max3f(c[1], c[2], c[3]);
  float m5 = max3f(d[0], d[1], d[2]);
  float r1 = max3f(m1, m2, m3);
  float r2 = max3f(m4, m5, d[3]);
  return fmaxf(r1, r2);
}

__device__ __forceinline__ void async_copy16(void* lds, const void* g) {
  __builtin_amdgcn_global_load_lds(
      (const __attribute__((address_space(1))) unsigned int*)g,
      (__attribute__((address_space(3))) unsigned int*)lds, 16, 0, 0);
}

// ---------------------------------------------------------------------------
// ALL fp32 -> bf16 conversions in one launch.
// ---------------------------------------------------------------------------
__global__ __launch_bounds__(256) void f2ball_kernel(
    const float* __restrict__ x, unsigned short* __restrict__ xb,
    const float* __restrict__ w0, const float* __restrict__ w1,
    const float* __restrict__ w2, const float* __restrict__ w3,
    unsigned short* __restrict__ o0, unsigned short* __restrict__ o1,
    unsigned short* __restrict__ o2, unsigned short* __restrict__ o3) {
  const float* in;
  unsigned short* out;
  long i;
  if (blockIdx.x < 8192) {
    in = x;
    out = xb;
    i = (long)blockIdx.x * 256 + threadIdx.x;
  } else {
    int wb = blockIdx.x - 8192;
    int which = wb >> 10;
    in = (which == 0) ? w0 : (which == 1) ? w1 : (which == 2) ? w2 : w3;
    out = (which == 0) ? o0 : (which == 1) ? o1 : (which == 2) ? o2 : o3;
    i = (long)(wb & 1023) * 256 + threadIdx.x;
  }
  float4 v = ((const float4*)in)[i];
  short4v o;
  o[0] = (short)f2bf(v.x);
  o[1] = (short)f2bf(v.y);
  o[2] = (short)f2bf(v.z);
  o[3] = (short)f2bf(v.w);
  *(short4v*)(out + i * 4) = o;
}

// ---------------------------------------------------------------------------
// Double-buffered 2-phase GEMM mainloop, 128x128 (kept for out_gemm).
// ---------------------------------------------------------------------------
__device__ __forceinline__ void gemm128_mainloop_db(
    const unsigned short* __restrict__ A, const unsigned short* __restrict__ Bt,
    int K, long brow, long bcol, unsigned short* As, unsigned short* Bs,
    floatx4 acc[4][4]) {
  const int tid = threadIdx.x;
  const int wave = tid >> 6;
  const int lane = tid & 63;
  const int wr = wave >> 1, wc = wave & 1;
  const int lr = lane & 15, lg = lane >> 4;

  const unsigned short* ga = A + (brow + (tid >> 2)) * (long)K + (tid & 3) * 8;
  const unsigned short* gb = Bt + (bcol + (tid >> 2)) * (long)K + (tid & 3) * 8;
  const int woff = wave * 512;
  const int a_off = (wr * 64 + lr) * 32 + lg * 8;
  const int b_off = (wc * 64 + lr) * 32 + lg * 8;

  async_copy16(As + woff, ga);
  async_copy16(As + woff + 2048, ga + (long)64 * K);
  async_copy16(Bs + woff, gb);
  async_copy16(Bs + woff + 2048, gb + (long)64 * K);
  ga += 32;
  gb += 32;
  __syncthreads();

  int buf = 0;
  for (int kt = 0; kt < K; kt += 32) {
    if (kt + 32 < K) {
      unsigned short* lA = As + (buf ^ 1) * 4096 + woff;
      unsigned short* lB = Bs + (buf ^ 1) * 4096 + woff;
      async_copy16(lA, ga);
      async_copy16(lA + 2048, ga + (long)64 * K);
      async_copy16(lB, gb);
      async_copy16(lB + 2048, gb + (long)64 * K);
      ga += 32;
      gb += 32;
    }
    const unsigned short* Ab = As + buf * 4096;
    const unsigned short* Bb = Bs + buf * 4096;
    short8 af[4], bf[4];
#pragma unroll
    for (int i = 0; i < 4; ++i) {
      af[i] = *(const short8*)(Ab + a_off + i * 512);
      bf[i] = *(const short8*)(Bb + b_off + i * 512);
    }
#pragma unroll
    for (int i = 0; i < 4; ++i)
#pragma unroll
      for (int j = 0; j < 4; ++j)
        acc[i][j] = __builtin_amdgcn_mfma_f32_16x16x32_bf16(af[i], bf[j], acc[i][j], 0, 0, 0);
    __syncthreads();
    buf ^= 1;
  }
}

// ---------------------------------------------------------------------------
// QKV projection, 128x256 tile (32 MFMA per K-step per wave). Q pre-scaled
// to log2 units; V-epilogue transposes via LDS in two 128-col halves.
// Grid: (64, 12). LDS 48 KB -> 3 blocks/CU.
// ---------------------------------------------------------------------------
__global__ __launch_bounds__(256, 2) void qkv_gemm256(
    const unsigned short* __restrict__ xb, const unsigned short* __restrict__ wqkv,
    const float* __restrict__ bq, const float* __restrict__ bk,
    const float* __restrict__ bv, unsigned short* __restrict__ q_out,
    unsigned short* __restrict__ k_out, unsigned short* __restrict__ vt_out) {
  __shared__ __align__(16) unsigned short Sh[24576];  // 48 KB
  unsigned short* As = Sh;          // [2][128][32] = 8192 elems
  unsigned short* Bs = Sh + 8192;   // [2][256][32] = 16384 elems

  const int tid = threadIdx.x;
  const int wave = tid >> 6, lane = tid & 63;
  const int wr = wave >> 1, wc = wave & 1;
  const int lr = lane & 15, lg = lane >> 4;

  const long brow = (long)blockIdx.x * 128;
  const long bcol = (long)blockIdx.y * 256;

  floatx4 zero = {0.f, 0.f, 0.f, 0.f};
  floatx4 acc[4][8];
#pragma unroll
  for (int i = 0; i < 4; ++i)
#pragma unroll
    for (int j = 0; j < 8; ++j) acc[i][j] = zero;

  const int K = 1024;
  const unsigned short* ga = xb + (brow + (tid >> 2)) * (long)K + (tid & 3) * 8;
  const unsigned short* gb = wqkv + (bcol + (tid >> 2)) * (long)K + (tid & 3) * 8;
  const int woff = wave * 512;
  const int a_off = (wr * 64 + lr) * 32 + lg * 8;
  const int b_off = (wc * 128 + lr) * 32 + lg * 8;

  // prologue: tile 0 -> buf 0
  async_copy16(As + woff, ga);
  async_copy16(As + woff + 2048, ga + (long)64 * K);
#pragma unroll
  for (int jj = 0; jj < 4; ++jj)
    async_copy16(Bs + woff + jj * 2048, gb + (long)jj * 64 * K);
  ga += 32;
  gb += 32;
  __syncthreads();

  int buf = 0;
  for (int kt = 0; kt < K; kt += 32) {
    if (kt + 32 < K) {
      unsigned short* lA = As + (buf ^ 1) * 4096 + woff;
      unsigned short* lB = Bs + (buf ^ 1) * 8192 + woff;
      async_copy16(lA, ga);
      async_copy16(lA + 2048, ga + (long)64 * K);
#pragma unroll
      for (int jj = 0; jj < 4; ++jj)
        async_copy16(lB + jj * 2048, gb + (long)jj * 64 * K);
      ga += 32;
      gb += 32;
    }
    const unsigned short* Ab = As + buf * 4096;
    const unsigned short* Bb = Bs + buf * 8192;
    short8 av[4], bvf[8];
#pragma unroll
    for (int i = 0; i < 4; ++i) av[i] = *(const short8*)(Ab + a_off + i * 512);
#pragma unroll
    for (int j = 0; j < 8; ++j) bvf[j] = *(const short8*)(Bb + b_off + j * 512);
    __builtin_amdgcn_s_setprio(1);
#pragma unroll
    for (int i = 0; i < 4; ++i)
#pragma unroll
      for (int j = 0; j < 8; ++j)
        acc[i][j] = __builtin_amdgcn_mfma_f32_16x16x32_bf16(av[i], bvf[j], acc[i][j], 0, 0, 0);
    __builtin_amdgcn_s_setprio(0);
    __syncthreads();
    buf ^= 1;
  }

  const int kind = (int)(bcol >> 10);  // 0=Q 1=K 2=V (256 | 1024)
  const float* bias = (kind == 0) ? bq : (kind == 1 ? bk : bv);

  if (kind == 2) {
    // two 128-col halves, transposed through Sh[128][136]
#pragma unroll 1
    for (int half = 0; half < 2; ++half) {
      if (wc == half) {
#pragma unroll
        for (int i = 0; i < 4; ++i)
#pragma unroll
          for (int j = 0; j < 8; ++j) {
            int n_local = j * 16 + lr;  // 0..127 within this half
            int m_base = wr * 64 + i * 16 + lg * 4;
            float bsc = bias[(int)((bcol + half * 128 + n_local) & 1023)];
            short4v pk;
#pragma unroll
            for (int r = 0; r < 4; ++r) pk[r] = (short)f2bf(acc[i][j][r] + bsc);
            *(short4v*)(Sh + n_local * 136 + m_base) = pk;
          }
      }
      __syncthreads();
      const int b = (int)(brow >> 11);
      const int t0 = (int)(brow & 2047);
      const int f0h = (int)(bcol - 2048) + half * 128;
#pragma unroll
      for (int p = 0; p < 8; ++p) {
        int c = p * 256 + tid;
        int d_loc = c >> 4, tc = c & 15;
        short8 v = *(const short8*)(Sh + d_loc * 136 + tc * 8);
        int h = (f0h >> 6) + (d_loc >> 6);
        int d = d_loc & 63;
        *(short8*)(vt_out + ((long)((b * 16 + h) * 64 + d)) * 2048 + t0 + tc * 8) = v;
      }
      __syncthreads();
    }
  } else {
#pragma unroll
    for (int i = 0; i < 4; ++i)
#pragma unroll
      for (int j = 0; j < 8; ++j)
#pragma unroll
        for (int r = 0; r < 4; ++r) {
          int m = (int)brow + wr * 64 + i * 16 + lg * 4 + r;
          int n = (int)bcol + wc * 128 + j * 16 + lr;
          int f = n & 1023;
          float v = acc[i][j][r] + bias[f];
          if (kind == 0) v *= QSCALE;
          unsigned short o = f2bf(v);
          int h = f >> 6, d = f & 63;
          int bb = m >> 11, t = m & 2047;
          long bh = (long)(bb * 16 + h);
          if (kind == 0)
            q_out[(bh * 2048 + t) * 64 + d] = o;
          else
            k_out[(bh * 2048 + t) * 64 + d] = o;
        }
  }
}

// ---------------------------------------------------------------------------
// Output projection (unchanged 128x128)
// ---------------------------------------------------------------------------
__global__ __launch_bounds__(256, 4) void out_gemm(
    const unsigned short* __restrict__ ob, const unsigned short* __restrict__ wo,
    const float* __restrict__ bo, float* __restrict__ out) {
  __shared__ unsigned short As[2 * 128 * 32];
  __shared__ unsigned short Bs[2 * 128 * 32];
  floatx4 zero = {0.f, 0.f, 0.f, 0.f};
  floatx4 acc[4][4];
#pragma unroll
  for (int i = 0; i < 4; ++i)
#pragma unroll
    for (int j = 0; j < 4; ++j) acc[i][j] = zero;

  long brow = (long)blockIdx.x * 128;
  long bcol = (long)blockIdx.y * 128;
  gemm128_mainloop_db(ob, wo, 1024, brow, bcol, As, Bs, acc);

  const int wave = threadIdx.x >> 6, lane = threadIdx.x & 63;
  const int wr = wave >> 1, wc = wave & 1, lr = lane & 15, lg = lane >> 4;
#pragma unroll
  for (int i = 0; i < 4; ++i)
#pragma unroll
    for (int j = 0; j < 4; ++j)
#pragma unroll
      for (int r = 0; r < 4; ++r) {
        int m = (int)brow + wr * 64 + i * 16 + lg * 4 + r;
        int n = (int)bcol + wc * 64 + j * 16 + lr;
        out[(long)m * 1024 + n] = acc[i][j][r] + bo[n];
      }
}

// ---------------------------------------------------------------------------
// Flash attention v10 (round-13 best): 4 waves x 32 q-rows, KVBLK=64 dbuf,
// 48 KB LDS, 3 blocks/CU, 1024-block LPT grid, l-via-MFMA(ones), v_max3,
// per-wave tile skip.
// ---------------------------------------------------------------------------
__device__ __forceinline__ void stage_kv(char* __restrict__ Kb, char* __restrict__ Vb,
                                         const char* __restrict__ Kp,
                                         const char* __restrict__ Vt, int kv0,
                                         int tid) {
  const int wave = tid >> 6;
#pragma unroll
  for (int j = 0; j < 2; ++j) {
    int d = j * 256 + tid;  // chunk id 0..511
    int row = d >> 3, cc = d & 7;
    int gc = cc ^ (row & 7);
    const char* gk = Kp + (size_t)kv0 * 128 + row * 128 + gc * 16;
    async_copy16(Kb + (j * 256 + wave * 64) * 16, gk);
    const char* gv = Vt + (size_t)row * 4096 + (size_t)kv0 * 2 + gc * 16;
    async_copy16(Vb + (j * 256 + wave * 64) * 16, gv);
  }
}

__device__ __forceinline__ void attn_step(
    const char* __restrict__ Kb, const char* __restrict__ Vb,
    char* __restrict__ PTw, const short8 (&qf)[2][2],
    int kv0, int q0, int lr, int lg, bool diag,
    float (&m_i)[2], floatx4 (&accL)[2], floatx4 (&accO)[2][4]) {
  floatx4 zero = {0.f, 0.f, 0.f, 0.f};
  const int x7 = lr & 7;
  floatx4 s[2][4];
  __builtin_amdgcn_s_setprio(1);
#pragma unroll
  for (int nt = 0; nt < 4; ++nt) {
    const char* kr = Kb + (nt * 16 + lr) * 128;
    short8 kf0 = *(const short8*)(kr + ((lg ^ x7) * 16));
    short8 kf1 = *(const short8*)(kr + (((4 + lg) ^ x7) * 16));
#pragma unroll
    for (int qa = 0; qa < 2; ++qa) {
      floatx4 a = zero;
      a = __builtin_amdgcn_mfma_f32_16x16x32_bf16(kf0, qf[qa][0], a, 0, 0, 0);
      a = __builtin_amdgcn_mfma_f32_16x16x32_bf16(kf1, qf[qa][1], a, 0, 0, 0);
      s[qa][nt] = a;
    }
  }
  __builtin_amdgcn_s_setprio(0);

  if (diag) {
#pragma unroll
    for (int qa = 0; qa < 2; ++qa) {
      const int q = q0 + qa * 16 + lr;
#pragma unroll
      for (int nt = 0; nt < 4; ++nt)
#pragma unroll
        for (int r = 0; r < 4; ++r) {
          int kvi = kv0 + nt * 16 + lg * 4 + r;
          if (kvi > q) s[qa][nt][r] = -1e30f;
        }
    }
  }

  float pmax[2];
#pragma unroll
  for (int qa = 0; qa < 2; ++qa)
    pmax[qa] = max16(s[qa][0], s[qa][1], s[qa][2], s[qa][3]);

  float g = fmaxf(pmax[0] - m_i[0], pmax[1] - m_i[1]);
  if (__any(g > 11.5f)) {
#pragma unroll
    for (int qa = 0; qa < 2; ++qa) {
      float mx = fmaxf(pmax[qa], __shfl_xor(pmax[qa], 16));
      mx = fmaxf(mx, __shfl_xor(mx, 32));
      float mnew = fmaxf(m_i[qa], mx);
      float scl = exp2f(m_i[qa] - mnew);
      m_i[qa] = mnew;
#pragma unroll
      for (int r = 0; r < 4; ++r) {
        float so = __shfl(scl, lg * 4 + r);
        accL[qa][r] *= so;
#pragma unroll
        for (int dt = 0; dt < 4; ++dt) accO[qa][dt][r] *= so;
      }
    }
  }

#pragma unroll
  for (int qa = 0; qa < 2; ++qa) {
    char* prow = PTw + (qa * 16 + lr) * 128;
#pragma unroll
    for (int nt = 0; nt < 4; ++nt) {
      float p0 = exp2f(s[qa][nt][0] - m_i[qa]);
      float p1 = exp2f(s[qa][nt][1] - m_i[qa]);
      float p2 = exp2f(s[qa][nt][2] - m_i[qa]);
      float p3 = exp2f(s[qa][nt][3] - m_i[qa]);
      uint2 wv;
      wv.x = cvt_pk_bf16(p0, p1);
      wv.y = cvt_pk_bf16(p2, p3);
      *(uint2*)(prow + (((2 * nt + (lg >> 1)) ^ x7) * 16) + ((2 * lg) & 3) * 4) = wv;
    }
  }

  short8 ones;
#pragma unroll
  for (int j = 0; j < 8; ++j) ones[j] = (short)0x3F80;

  __builtin_amdgcn_s_setprio(1);
#pragma unroll
  for (int kk = 0; kk < 2; ++kk) {
    short8 pf0 = *(const short8*)(PTw + lr * 128 + (((4 * kk + lg) ^ x7) * 16));
    short8 pf1 = *(const short8*)(PTw + (16 + lr) * 128 + (((4 * kk + lg) ^ x7) * 16));
#pragma unroll
    for (int dt = 0; dt < 4; ++dt) {
      short8 vf = *(const short8*)(Vb + (dt * 16 + lr) * 128 + (((4 * kk + lg) ^ x7) * 16));
      accO[0][dt] = __builtin_amdgcn_mfma_f32_16x16x32_bf16(pf0, vf, accO[0][dt], 0, 0, 0);
      accO[1][dt] = __builtin_amdgcn_mfma_f32_16x16x32_bf16(pf1, vf, accO[1][dt], 0, 0, 0);
    }
    accL[0] = __builtin_amdgcn_mfma_f32_16x16x32_bf16(pf0, ones, accL[0], 0, 0, 0);
    accL[1] = __builtin_amdgcn_mfma_f32_16x16x32_bf16(pf1, ones, accL[1], 0, 0, 0);
  }
  __builtin_amdgcn_s_setprio(0);
}

__global__ __launch_bounds__(256, 3) void attn_fwd(
    const unsigned short* __restrict__ qb, const unsigned short* __restrict__ kb,
    const unsigned short* __restrict__ vtb, unsigned short* __restrict__ ob) {
  __shared__ __align__(16) char Kbuf[2][8192];
  __shared__ __align__(16) char Vbuf[2][8192];
  __shared__ __align__(16) char PTbuf[4][4096];

  const int id = blockIdx.x;
  const int qt = 15 - (id >> 6);
  const int bh = id & 63;

  const int tid = threadIdx.x;
  const int wave = tid >> 6, lane = tid & 63;
  const int lr = lane & 15, lg = lane >> 4;
  const unsigned short* Q = qb + (long)bh * 2048 * 64;
  const char* Kp = (const char*)(kb + (long)bh * 2048 * 64);
  const char* Vt = (const char*)(vtb + (long)bh * 64 * 2048);
  const int b = bh >> 4, h = bh & 15;
  char* PTw = PTbuf[wave];

  floatx4 zero = {0.f, 0.f, 0.f, 0.f};

  const int q0 = qt * 128 + wave * 32;
  const int nkv = 2 * qt + 2;

  short8 qf[2][2];
#pragma unroll
  for (int qa = 0; qa < 2; ++qa)
#pragma unroll
    for (int kk = 0; kk < 2; ++kk)
      qf[qa][kk] = *(const short8*)(Q + (q0 + qa * 16 + lr) * 64 + kk * 32 + lg * 8);

  floatx4 accO[2][4];
  floatx4 accL[2];
#pragma unroll
  for (int qa = 0; qa < 2; ++qa) {
    accL[qa] = zero;
#pragma unroll
    for (int dt = 0; dt < 4; ++dt) accO[qa][dt] = zero;
  }
  float m_i[2] = {-1e30f, -1e30f};

  stage_kv(Kbuf[0], Vbuf[0], Kp, Vt, 0, tid);
  __syncthreads();
#pragma unroll 1
  for (int kv = 0; kv < nkv; ++kv) {
    if (kv + 1 < nkv)
      stage_kv(Kbuf[(kv + 1) & 1], Vbuf[(kv + 1) & 1], Kp, Vt, (kv + 1) * 64, tid);
    const int kv0 = kv * 64;
    if (kv0 < q0 + 32)
      attn_step(Kbuf[kv & 1], Vbuf[kv & 1], PTw, qf, kv0, q0, lr, lg,
                kv0 + 64 > q0, m_i, accL, accO);
    __syncthreads();
  }

#pragma unroll
  for (int qa = 0; qa < 2; ++qa) {
#pragma unroll
    for (int r = 0; r < 4; ++r) {
      float io = 1.f / accL[qa][r];
      int tq = q0 + qa * 16 + 4 * lg + r;
#pragma unroll
      for (int dt = 0; dt < 4; ++dt)
        ob[((long)b * 2048 + tq) * 1024 + h * 64 + dt * 16 + lr] =
            f2bf(accO[qa][dt][r] * io);
    }
  }
}

// ---------------------------------------------------------------------------
extern "C" void kernel_launch(void* const* d_in, const int* in_sizes, int n_in,
                              void* d_out, int out_size, void* d_ws, size_t ws_size,
                              hipStream_t stream) {
  const float* x = (const float*)d_in[0];
  const float* bq = (const float*)d_in[2];
  const float* bk = (const float*)d_in[4];
  const float* bv = (const float*)d_in[6];
  const float* bo = (const float*)d_in[8];
  float* out = (float*)d_out;

  char* ws = (char*)d_ws;
  unsigned short* xb = (unsigned short*)(ws);                  // 16 MB  [8192][1024]
  unsigned short* wqkv = (unsigned short*)(ws + (16l << 20));  // 6 MB   [3072][1024]
  unsigned short* wob = (unsigned short*)(ws + (22l << 20));   // 2 MB   [1024][1024]
  unsigned short* qb = (unsigned short*)(ws + (24l << 20));    // 16 MB  [64][2048][64]
  unsigned short* kb = (unsigned short*)(ws + (40l << 20));    // 16 MB  [64][2048][64]
  unsigned short* vtb = (unsigned short*)(ws + (56l << 20));   // 16 MB  [64][64][2048]
  unsigned short* ob = (unsigned short*)(ws + (72l << 20));    // 16 MB  [8192][1024]

  f2ball_kernel<<<12288, 256, 0, stream>>>(
      x, xb, (const float*)d_in[1], (const float*)d_in[3], (const float*)d_in[5],
      (const float*)d_in[7], wqkv, wqkv + (1l << 20), wqkv + (2l << 20), wob);

  qkv_gemm256<<<dim3(64, 12), 256, 0, stream>>>(xb, wqkv, bq, bk, bv, qb, kb, vtb);
  attn_fwd<<<1024, 256, 0, stream>>>(qb, kb, vtb, ob);
  out_gemm<<<dim3(64, 8), 256, 0, stream>>>(ob, wob, bo, out);
}

// Round 16
// 163.519 us; speedup vs baseline: 1.6735x; 1.0052x over previous
//
#include <hip/hip_runtime.h>
#include <stdint.h>

typedef __attribute__((ext_vector_type(8))) short short8;
typedef __attribute__((ext_vector_type(4))) short short4v;
typedef __attribute__((ext_vector_type(4))) float floatx4;
typedef __attribute__((ext_vector_type(16))) float floatx16;

#define QSCALE 0.1803368801111f /* 0.125 * log2(e): S in log2 units */

__device__ __forceinline__ unsigned short f2bf(float f) {
  unsigned int u = __float_as_uint(f);
  unsigned int r = (u + 0x7FFFu + ((u >> 16) & 1u)) >> 16;  // RNE
  return (unsigned short)r;
}

__device__ __forceinline__ unsigned int cvt_pk_bf16(float lo, float hi) {
  unsigned int r;
  asm("v_cvt_pk_bf16_f32 %0, %1, %2" : "=v"(r) : "v"(lo), "v"(hi));
  return r;
}

__device__ __forceinline__ float max3f(float a, float b, float c) {
  float r;
  asm("v_max3_f32 %0, %1, %2, %3" : "=v"(r) : "v"(a), "v"(b), "v"(c));
  return r;
}

__device__ __forceinline__ void async_copy16(void* lds, const void* g) {
  __builtin_amdgcn_global_load_lds(
      (const __attribute__((address_space(1))) unsigned int*)g,
      (__attribute__((address_space(3))) unsigned int*)lds, 16, 0, 0);
}

// ---------------------------------------------------------------------------
// ALL fp32 -> bf16 conversions in one launch.
// ---------------------------------------------------------------------------
__global__ __launch_bounds__(256) void f2ball_kernel(
    const float* __restrict__ x, unsigned short* __restrict__ xb,
    const float* __restrict__ w0, const float* __restrict__ w1,
    const float* __restrict__ w2, const float* __restrict__ w3,
    unsigned short* __restrict__ o0, unsigned short* __restrict__ o1,
    unsigned short* __restrict__ o2, unsigned short* __restrict__ o3) {
  const float* in;
  unsigned short* out;
  long i;
  if (blockIdx.x < 8192) {
    in = x;
    out = xb;
    i = (long)blockIdx.x * 256 + threadIdx.x;
  } else {
    int wb = blockIdx.x - 8192;
    int which = wb >> 10;
    in = (which == 0) ? w0 : (which == 1) ? w1 : (which == 2) ? w2 : w3;
    out = (which == 0) ? o0 : (which == 1) ? o1 : (which == 2) ? o2 : o3;
    i = (long)(wb & 1023) * 256 + threadIdx.x;
  }
  float4 v = ((const float4*)in)[i];
  short4v o;
  o[0] = (short)f2bf(v.x);
  o[1] = (short)f2bf(v.y);
  o[2] = (short)f2bf(v.z);
  o[3] = (short)f2bf(v.w);
  *(short4v*)(out + i * 4) = o;
}

// ---------------------------------------------------------------------------
// Double-buffered 2-phase GEMM mainloop, 128x128 (kept for out_gemm).
// ---------------------------------------------------------------------------
__device__ __forceinline__ void gemm128_mainloop_db(
    const unsigned short* __restrict__ A, const unsigned short* __restrict__ Bt,
    int K, long brow, long bcol, unsigned short* As, unsigned short* Bs,
    floatx4 acc[4][4]) {
  const int tid = threadIdx.x;
  const int wave = tid >> 6;
  const int lane = tid & 63;
  const int wr = wave >> 1, wc = wave & 1;
  const int lr = lane & 15, lg = lane >> 4;

  const unsigned short* ga = A + (brow + (tid >> 2)) * (long)K + (tid & 3) * 8;
  const unsigned short* gb = Bt + (bcol + (tid >> 2)) * (long)K + (tid & 3) * 8;
  const int woff = wave * 512;
  const int a_off = (wr * 64 + lr) * 32 + lg * 8;
  const int b_off = (wc * 64 + lr) * 32 + lg * 8;

  async_copy16(As + woff, ga);
  async_copy16(As + woff + 2048, ga + (long)64 * K);
  async_copy16(Bs + woff, gb);
  async_copy16(Bs + woff + 2048, gb + (long)64 * K);
  ga += 32;
  gb += 32;
  __syncthreads();

  int buf = 0;
  for (int kt = 0; kt < K; kt += 32) {
    if (kt + 32 < K) {
      unsigned short* lA = As + (buf ^ 1) * 4096 + woff;
      unsigned short* lB = Bs + (buf ^ 1) * 4096 + woff;
      async_copy16(lA, ga);
      async_copy16(lA + 2048, ga + (long)64 * K);
      async_copy16(lB, gb);
      async_copy16(lB + 2048, gb + (long)64 * K);
      ga += 32;
      gb += 32;
    }
    const unsigned short* Ab = As + buf * 4096;
    const unsigned short* Bb = Bs + buf * 4096;
    short8 af[4], bf[4];
#pragma unroll
    for (int i = 0; i < 4; ++i) {
      af[i] = *(const short8*)(Ab + a_off + i * 512);
      bf[i] = *(const short8*)(Bb + b_off + i * 512);
    }
#pragma unroll
    for (int i = 0; i < 4; ++i)
#pragma unroll
      for (int j = 0; j < 4; ++j)
        acc[i][j] = __builtin_amdgcn_mfma_f32_16x16x32_bf16(af[i], bf[j], acc[i][j], 0, 0, 0);
    __syncthreads();
    buf ^= 1;
  }
}

// ---------------------------------------------------------------------------
// QKV projection, 128x256 tile. Q pre-scaled to log2 units; V-epilogue
// transposes via LDS in two 128-col halves. Grid (64,12), 48 KB LDS.
// ---------------------------------------------------------------------------
__global__ __launch_bounds__(256, 2) void qkv_gemm256(
    const unsigned short* __restrict__ xb, const unsigned short* __restrict__ wqkv,
    const float* __restrict__ bq, const float* __restrict__ bk,
    const float* __restrict__ bv, unsigned short* __restrict__ q_out,
    unsigned short* __restrict__ k_out, unsigned short* __restrict__ vt_out) {
  __shared__ __align__(16) unsigned short Sh[24576];  // 48 KB
  unsigned short* As = Sh;          // [2][128][32]
  unsigned short* Bs = Sh + 8192;   // [2][256][32]

  const int tid = threadIdx.x;
  const int wave = tid >> 6, lane = tid & 63;
  const int wr = wave >> 1, wc = wave & 1;
  const int lr = lane & 15, lg = lane >> 4;

  const long brow = (long)blockIdx.x * 128;
  const long bcol = (long)blockIdx.y * 256;

  floatx4 zero = {0.f, 0.f, 0.f, 0.f};
  floatx4 acc[4][8];
#pragma unroll
  for (int i = 0; i < 4; ++i)
#pragma unroll
    for (int j = 0; j < 8; ++j) acc[i][j] = zero;

  const int K = 1024;
  const unsigned short* ga = xb + (brow + (tid >> 2)) * (long)K + (tid & 3) * 8;
  const unsigned short* gb = wqkv + (bcol + (tid >> 2)) * (long)K + (tid & 3) * 8;
  const int woff = wave * 512;
  const int a_off = (wr * 64 + lr) * 32 + lg * 8;
  const int b_off = (wc * 128 + lr) * 32 + lg * 8;

  async_copy16(As + woff, ga);
  async_copy16(As + woff + 2048, ga + (long)64 * K);
#pragma unroll
  for (int jj = 0; jj < 4; ++jj)
    async_copy16(Bs + woff + jj * 2048, gb + (long)jj * 64 * K);
  ga += 32;
  gb += 32;
  __syncthreads();

  int buf = 0;
  for (int kt = 0; kt < K; kt += 32) {
    if (kt + 32 < K) {
      unsigned short* lA = As + (buf ^ 1) * 4096 + woff;
      unsigned short* lB = Bs + (buf ^ 1) * 8192 + woff;
      async_copy16(lA, ga);
      async_copy16(lA + 2048, ga + (long)64 * K);
#pragma unroll
      for (int jj = 0; jj < 4; ++jj)
        async_copy16(lB + jj * 2048, gb + (long)jj * 64 * K);
      ga += 32;
      gb += 32;
    }
    const unsigned short* Ab = As + buf * 4096;
    const unsigned short* Bb = Bs + buf * 8192;
    short8 av[4], bvf[8];
#pragma unroll
    for (int i = 0; i < 4; ++i) av[i] = *(const short8*)(Ab + a_off + i * 512);
#pragma unroll
    for (int j = 0; j < 8; ++j) bvf[j] = *(const short8*)(Bb + b_off + j * 512);
    __builtin_amdgcn_s_setprio(1);
#pragma unroll
    for (int i = 0; i < 4; ++i)
#pragma unroll
      for (int j = 0; j < 8; ++j)
        acc[i][j] = __builtin_amdgcn_mfma_f32_16x16x32_bf16(av[i], bvf[j], acc[i][j], 0, 0, 0);
    __builtin_amdgcn_s_setprio(0);
    __syncthreads();
    buf ^= 1;
  }

  const int kind = (int)(bcol >> 10);
  const float* bias = (kind == 0) ? bq : (kind == 1 ? bk : bv);

  if (kind == 2) {
#pragma unroll 1
    for (int half = 0; half < 2; ++half) {
      if (wc == half) {
#pragma unroll
        for (int i = 0; i < 4; ++i)
#pragma unroll
          for (int j = 0; j < 8; ++j) {
            int n_local = j * 16 + lr;
            int m_base = wr * 64 + i * 16 + lg * 4;
            float bsc = bias[(int)((bcol + half * 128 + n_local) & 1023)];
            short4v pk;
#pragma unroll
            for (int r = 0; r < 4; ++r) pk[r] = (short)f2bf(acc[i][j][r] + bsc);
            *(short4v*)(Sh + n_local * 136 + m_base) = pk;
          }
      }
      __syncthreads();
      const int b = (int)(brow >> 11);
      const int t0 = (int)(brow & 2047);
      const int f0h = (int)(bcol - 2048) + half * 128;
#pragma unroll
      for (int p = 0; p < 8; ++p) {
        int c = p * 256 + tid;
        int d_loc = c >> 4, tc = c & 15;
        short8 v = *(const short8*)(Sh + d_loc * 136 + tc * 8);
        int h = (f0h >> 6) + (d_loc >> 6);
        int d = d_loc & 63;
        *(short8*)(vt_out + ((long)((b * 16 + h) * 64 + d)) * 2048 + t0 + tc * 8) = v;
      }
      __syncthreads();
    }
  } else {
#pragma unroll
    for (int i = 0; i < 4; ++i)
#pragma unroll
      for (int j = 0; j < 8; ++j)
#pragma unroll
        for (int r = 0; r < 4; ++r) {
          int m = (int)brow + wr * 64 + i * 16 + lg * 4 + r;
          int n = (int)bcol + wc * 128 + j * 16 + lr;
          int f = n & 1023;
          float v = acc[i][j][r] + bias[f];
          if (kind == 0) v *= QSCALE;
          unsigned short o = f2bf(v);
          int h = f >> 6, d = f & 63;
          int bb = m >> 11, t = m & 2047;
          long bh = (long)(bb * 16 + h);
          if (kind == 0)
            q_out[(bh * 2048 + t) * 64 + d] = o;
          else
            k_out[(bh * 2048 + t) * 64 + d] = o;
        }
  }
}

// ---------------------------------------------------------------------------
// Output projection (unchanged 128x128)
// ---------------------------------------------------------------------------
__global__ __launch_bounds__(256, 4) void out_gemm(
    const unsigned short* __restrict__ ob, const unsigned short* __restrict__ wo,
    const float* __restrict__ bo, float* __restrict__ out) {
  __shared__ unsigned short As[2 * 128 * 32];
  __shared__ unsigned short Bs[2 * 128 * 32];
  floatx4 zero = {0.f, 0.f, 0.f, 0.f};
  floatx4 acc[4][4];
#pragma unroll
  for (int i = 0; i < 4; ++i)
#pragma unroll
    for (int j = 0; j < 4; ++j) acc[i][j] = zero;

  long brow = (long)blockIdx.x * 128;
  long bcol = (long)blockIdx.y * 128;
  gemm128_mainloop_db(ob, wo, 1024, brow, bcol, As, Bs, acc);

  const int wave = threadIdx.x >> 6, lane = threadIdx.x & 63;
  const int wr = wave >> 1, wc = wave & 1, lr = lane & 15, lg = lane >> 4;
#pragma unroll
  for (int i = 0; i < 4; ++i)
#pragma unroll
    for (int j = 0; j < 4; ++j)
#pragma unroll
      for (int r = 0; r < 4; ++r) {
        int m = (int)brow + wr * 64 + i * 16 + lg * 4 + r;
        int n = (int)bcol + wc * 64 + j * 16 + lr;
        out[(long)m * 1024 + n] = acc[i][j][r] + bo[n];
      }
}

// ---------------------------------------------------------------------------
// Flash attention v11: 32x32 swapped-QK, fully in-register softmax (m214
// structure). 4 waves x 32 q-rows, KVBLK=64 dbuf, LDS 32 KB, 3 blocks/CU,
// 1024-block LPT grid. Per lane: q = q0 + (lane&31); S^T, P, l, m, rescale
// and epilogue all lane-local; P -> PV B-fragments via cvt_pk +
// v_permlane32_swap (no LDS P buffer).
// ---------------------------------------------------------------------------
__device__ __forceinline__ void stage_kv(char* __restrict__ Kb, char* __restrict__ Vb,
                                         const char* __restrict__ Kp,
                                         const char* __restrict__ Vt, int kv0,
                                         int tid) {
  const int wave = tid >> 6;
#pragma unroll
  for (int j = 0; j < 2; ++j) {
    int d = j * 256 + tid;  // chunk id 0..511
    int row = d >> 3, cc = d & 7;
    int gc = cc ^ (row & 7);
    const char* gk = Kp + (size_t)kv0 * 128 + row * 128 + gc * 16;
    async_copy16(Kb + (j * 256 + wave * 64) * 16, gk);
    const char* gv = Vt + (size_t)row * 4096 + (size_t)kv0 * 2 + gc * 16;
    async_copy16(Vb + (j * 256 + wave * 64) * 16, gv);
  }
}

// read a 32x16 A-fragment row slice from a swizzled [64][128B] LDS tile
__device__ __forceinline__ short8 read_frag(const char* __restrict__ base, int row,
                                            int chunk) {
  return *(const short8*)(base + row * 128 + ((chunk ^ (row & 7)) * 16));
}

__device__ __forceinline__ void attn_step(
    const char* __restrict__ Kb, const char* __restrict__ Vb,
    const short8 (&qf)[4], int kv0, int q0, int l31, int hi, bool diag,
    float& m_i, float& l_i, floatx16 (&accO)[2]) {
  // ---- QK^T (swapped): S^T[kv][q], two 32-kv halves ----
  floatx16 sh[2];
  __builtin_amdgcn_s_setprio(1);
#pragma unroll
  for (int hh = 0; hh < 2; ++hh) {
    floatx16 a = {0.f};
#pragma unroll
    for (int e = 1; e < 16; ++e) a[e] = 0.f;
#pragma unroll
    for (int ks = 0; ks < 4; ++ks) {
      short8 kf = read_frag(Kb, hh * 32 + l31, 2 * ks + hi);
      a = __builtin_amdgcn_mfma_f32_32x32x16_bf16(kf, qf[ks], a, 0, 0, 0);
    }
    sh[hh] = a;
  }
  __builtin_amdgcn_s_setprio(0);

  const int q = q0 + l31;
  if (diag) {
#pragma unroll
    for (int hh = 0; hh < 2; ++hh)
#pragma unroll
      for (int r = 0; r < 16; ++r) {
        int kvi = kv0 + 32 * hh + (r & 3) + 8 * (r >> 2) + 4 * hi;
        if (kvi > q) sh[hh][r] = -1e30f;
      }
  }

  // ---- in-lane row max over 32 values (lane's kv half-set) ----
  float t[11];
#pragma unroll
  for (int i = 0; i < 10; ++i)
    t[i] = max3f(sh[(3 * i) / 16][(3 * i) % 16], sh[(3 * i + 1) / 16][(3 * i + 1) % 16],
                 sh[(3 * i + 2) / 16][(3 * i + 2) % 16]);
  t[10] = fmaxf(sh[1][14], sh[1][15]);
  float pmax = max3f(max3f(t[0], t[1], t[2]), max3f(t[3], t[4], t[5]),
                     max3f(t[6], t[7], t[8]));
  pmax = max3f(pmax, t[9], t[10]);

  // defer-max: __any spans both kv-half lanes automatically
  if (__any(pmax > m_i + 11.5f)) {
    float mx = fmaxf(pmax, __shfl_xor(pmax, 32));
    float mnew = fmaxf(m_i, mx);
    float scl = exp2f(m_i - mnew);
    m_i = mnew;
    l_i *= scl;
#pragma unroll
    for (int dt = 0; dt < 2; ++dt)
#pragma unroll
      for (int r = 0; r < 16; ++r) accO[dt][r] *= scl;
  }

  // ---- P = exp2(S - m), in-lane l partial ----
  float p[32];
#pragma unroll
  for (int hh = 0; hh < 2; ++hh)
#pragma unroll
    for (int r = 0; r < 16; ++r) p[hh * 16 + r] = exp2f(sh[hh][r] - m_i);
  float ls = 0.f;
#pragma unroll
  for (int i = 0; i < 8; ++i)
    ls += (p[4 * i] + p[4 * i + 1]) + (p[4 * i + 2] + p[4 * i + 3]);
  l_i += ls;

  // ---- P -> B-fragments via cvt_pk + permlane32_swap ----
  short8 pb[4];
#pragma unroll
  for (int ks2 = 0; ks2 < 4; ++ks2) {
    const int ib = (ks2 >> 1) * 16 + (ks2 & 1) * 8;
    unsigned int a0 = cvt_pk_bf16(p[ib + 0], p[ib + 1]);
    unsigned int b0 = cvt_pk_bf16(p[ib + 4], p[ib + 5]);
    unsigned int a1 = cvt_pk_bf16(p[ib + 2], p[ib + 3]);
    unsigned int b1 = cvt_pk_bf16(p[ib + 6], p[ib + 7]);
    asm volatile("v_permlane32_swap_b32 %0, %1" : "+v"(a0), "+v"(b0));
    asm volatile("v_permlane32_swap_b32 %0, %1" : "+v"(a1), "+v"(b1));
    unsigned int w[4] = {a0, a1, b0, b1};
    pb[ks2] = *(const short8*)w;
  }

  // ---- PV: O^T[d][q] = mfma32(Vt-tile, P^T) ----
  __builtin_amdgcn_s_setprio(1);
#pragma unroll
  for (int dt = 0; dt < 2; ++dt)
#pragma unroll
    for (int ks2 = 0; ks2 < 4; ++ks2) {
      short8 vf = read_frag(Vb, dt * 32 + l31, 2 * ks2 + hi);
      accO[dt] = __builtin_amdgcn_mfma_f32_32x32x16_bf16(vf, pb[ks2], accO[dt], 0, 0, 0);
    }
  __builtin_amdgcn_s_setprio(0);
}

__global__ __launch_bounds__(256, 3) void attn_fwd(
    const unsigned short* __restrict__ qb, const unsigned short* __restrict__ kb,
    const unsigned short* __restrict__ vtb, unsigned short* __restrict__ ob) {
  __shared__ __align__(16) char Kbuf[2][8192];
  __shared__ __align__(16) char Vbuf[2][8192];

  // id = (15-qt)*64 + bh : LPT order; xcd = bh%8 keeps head L2 locality.
  const int id = blockIdx.x;
  const int qt = 15 - (id >> 6);
  const int bh = id & 63;

  const int tid = threadIdx.x;
  const int wave = tid >> 6, lane = tid & 63;
  const int l31 = lane & 31, hi = lane >> 5;
  const unsigned short* Q = qb + (long)bh * 2048 * 64;
  const char* Kp = (const char*)(kb + (long)bh * 2048 * 64);
  const char* Vt = (const char*)(vtb + (long)bh * 64 * 2048);
  const int b = bh >> 4, h = bh & 15;

  const int q0 = qt * 128 + wave * 32;  // this wave's 32 q-rows
  const int nkv = 2 * qt + 2;

  // Q B-fragments: col q = q0+l31, k = ks*16 + hi*8 + j
  short8 qf[4];
#pragma unroll
  for (int ks = 0; ks < 4; ++ks)
    qf[ks] = *(const short8*)(Q + (q0 + l31) * 64 + ks * 16 + hi * 8);

  floatx16 accO[2];
#pragma unroll
  for (int dt = 0; dt < 2; ++dt)
#pragma unroll
    for (int r = 0; r < 16; ++r) accO[dt][r] = 0.f;
  float m_i = -1e30f, l_i = 0.f;

  stage_kv(Kbuf[0], Vbuf[0], Kp, Vt, 0, tid);
  __syncthreads();
#pragma unroll 1
  for (int kv = 0; kv < nkv; ++kv) {
    if (kv + 1 < nkv)
      stage_kv(Kbuf[(kv + 1) & 1], Vbuf[(kv + 1) & 1], Kp, Vt, (kv + 1) * 64, tid);
    const int kv0 = kv * 64;
    if (kv0 < q0 + 32)  // skip tiles fully above this wave's rows
      attn_step(Kbuf[kv & 1], Vbuf[kv & 1], qf, kv0, q0, l31, hi,
                kv0 + 64 > q0, m_i, l_i, accO);
    __syncthreads();
  }

  // epilogue: combine the two kv-half partials of l, all else lane-local
  float lt = l_i + __shfl_xor(l_i, 32);
  float io = 1.f / lt;
  const int q = q0 + l31;
  unsigned short* orow = ob + ((long)b * 2048 + q) * 1024 + h * 64;
#pragma unroll
  for (int dt = 0; dt < 2; ++dt)
#pragma unroll
    for (int g = 0; g < 4; ++g) {
      short4v pk;
#pragma unroll
      for (int e = 0; e < 4; ++e) pk[e] = (short)f2bf(accO[dt][4 * g + e] * io);
      *(short4v*)(orow + dt * 32 + g * 8 + hi * 4) = pk;
    }
}

// ---------------------------------------------------------------------------
extern "C" void kernel_launch(void* const* d_in, const int* in_sizes, int n_in,
                              void* d_out, int out_size, void* d_ws, size_t ws_size,
                              hipStream_t stream) {
  const float* x = (const float*)d_in[0];
  const float* bq = (const float*)d_in[2];
  const float* bk = (const float*)d_in[4];
  const float* bv = (const float*)d_in[6];
  const float* bo = (const float*)d_in[8];
  float* out = (float*)d_out;

  char* ws = (char*)d_ws;
  unsigned short* xb = (unsigned short*)(ws);                  // 16 MB  [8192][1024]
  unsigned short* wqkv = (unsigned short*)(ws + (16l << 20));  // 6 MB   [3072][1024]
  unsigned short* wob = (unsigned short*)(ws + (22l << 20));   // 2 MB   [1024][1024]
  unsigned short* qb = (unsigned short*)(ws + (24l << 20));    // 16 MB  [64][2048][64]
  unsigned short* kb = (unsigned short*)(ws + (40l << 20));    // 16 MB  [64][2048][64]
  unsigned short* vtb = (unsigned short*)(ws + (56l << 20));   // 16 MB  [64][64][2048]
  unsigned short* ob = (unsigned short*)(ws + (72l << 20));    // 16 MB  [8192][1024]

  f2ball_kernel<<<12288, 256, 0, stream>>>(
      x, xb, (const float*)d_in[1], (const float*)d_in[3], (const float*)d_in[5],
      (const float*)d_in[7], wqkv, wqkv + (1l << 20), wqkv + (2l << 20), wob);

  qkv_gemm256<<<dim3(64, 12), 256, 0, stream>>>(xb, wqkv, bq, bk, bv, qb, kb, vtb);
  attn_fwd<<<1024, 256, 0, stream>>>(qb, kb, vtb, ob);
  out_gemm<<<dim3(64, 8), 256, 0, stream>>>(ob, wob, bo, out);
}